// Round 4
// baseline (805.401 us; speedup 1.0000x reference)
//
#include <hip/hip_runtime.h>
#include <hip/hip_bf16.h>
#include <math.h>

#define N_EMBED 1024
#define N_HEAD 16
#define HD 64
#define BB 4
#define TT 2048
#define NTOK (BB * TT)        // 8192 rows
#define QKV_LD (3 * N_EMBED)  // 3072

typedef __bf16 bf16x8 __attribute__((ext_vector_type(8)));
typedef float f32x4 __attribute__((ext_vector_type(4)));

__device__ __forceinline__ unsigned short f2bf(float f) {
    __hip_bfloat16 h = __float2bfloat16(f);
    return __builtin_bit_cast(unsigned short, h);
}

// async global->LDS, 16B per lane. LDS dest = wave-uniform base + lane*16.
__device__ __forceinline__ void gll16(const unsigned short* g, unsigned short* l) {
    __builtin_amdgcn_global_load_lds(
        (const __attribute__((address_space(1))) void*)g,
        (__attribute__((address_space(3))) void*)l,
        16, 0, 0);
}

// ---------------------------------------------------------------------------
// Weight transpose + fp32 -> bf16 convert:  in [K][N] fp32  ->  out [N][K] bf16
// ---------------------------------------------------------------------------
__global__ __launch_bounds__(256) void transpose_bf16_kernel(
    const float* __restrict__ in, unsigned short* __restrict__ out, int K, int N) {
    __shared__ float tile[32][33];
    int bx = blockIdx.x * 32;  // n base
    int by = blockIdx.y * 32;  // k base
    int tx = threadIdx.x, ty = threadIdx.y;
#pragma unroll
    for (int i = ty; i < 32; i += 8)
        tile[i][tx] = in[(size_t)(by + i) * N + bx + tx];
    __syncthreads();
#pragma unroll
    for (int i = ty; i < 32; i += 8)
        out[(size_t)(bx + i) * K + by + tx] = f2bf(tile[tx][i]);
}

// ---------------------------------------------------------------------------
// Pack K and V per (b,h,kv-tile) into contiguous 8KB chunks:
//   kpk[bh*32+tile][kv(64)][d(64)]  = K[b, tile*64+kv, h*64+d]
//   vpk[bh*32+tile][d(64)][kv(64)]  = V[b, tile*64+kv, h*64+d]   (transposed)
// One block per (bh,tile). 256 threads.
// ---------------------------------------------------------------------------
__global__ __launch_bounds__(256) void pack_kv_kernel(
    const unsigned short* __restrict__ qkv,
    unsigned short* __restrict__ kpk, unsigned short* __restrict__ vpk) {
    __shared__ unsigned short vt_[64][65];
    int blk = blockIdx.x;            // bh*32 + tile
    int bh = blk >> 5, tile = blk & 31;
    int b = bh >> 4, h = bh & 15;
    int t = threadIdx.x;
    int kv = t >> 2, dq = (t & 3) * 16;
    const unsigned short* base =
        qkv + (size_t)(b * TT + tile * 64 + kv) * QKV_LD + h * HD + dq;

    // K: straight copy into packed rows
    uint4 k0 = *reinterpret_cast<const uint4*>(base + N_EMBED);
    uint4 k1 = *reinterpret_cast<const uint4*>(base + N_EMBED + 8);
    unsigned short* kdst = kpk + (size_t)blk * 4096 + kv * 64 + dq;
    *reinterpret_cast<uint4*>(kdst) = k0;
    *reinterpret_cast<uint4*>(kdst + 8) = k1;

    // V: stage row-major in LDS, write transposed
    uint4 v0 = *reinterpret_cast<const uint4*>(base + 2 * N_EMBED);
    uint4 v1 = *reinterpret_cast<const uint4*>(base + 2 * N_EMBED + 8);
    unsigned short tmp[16];
    *reinterpret_cast<uint4*>(tmp) = v0;
    *reinterpret_cast<uint4*>(tmp + 8) = v1;
#pragma unroll
    for (int e = 0; e < 16; e++) vt_[kv][dq + e] = tmp[e];
    __syncthreads();
    int dd = t >> 2, kq = (t & 3) * 16;
    unsigned short o[16];
#pragma unroll
    for (int e = 0; e < 16; e++) o[e] = vt_[kq + e][dd];
    unsigned short* vdst = vpk + (size_t)blk * 4096 + dd * 64 + kq;
    *reinterpret_cast<uint4*>(vdst) = *reinterpret_cast<uint4*>(o);
    *reinterpret_cast<uint4*>(vdst + 8) = *reinterpret_cast<uint4*>(o + 8);
}

// ---------------------------------------------------------------------------
// Row LayerNorm: fp32 in [rows][1024] -> bf16 out
// ---------------------------------------------------------------------------
__global__ __launch_bounds__(256) void ln_kernel(
    const float* __restrict__ x, const float* __restrict__ w,
    const float* __restrict__ b, unsigned short* __restrict__ out) {
    int row = blockIdx.x;
    int t = threadIdx.x;
    const float* xr = x + (size_t)row * N_EMBED;
    float4 v = reinterpret_cast<const float4*>(xr)[t];
    float s = v.x + v.y + v.z + v.w;
    float s2 = v.x * v.x + v.y * v.y + v.z * v.z + v.w * v.w;
#pragma unroll
    for (int m = 1; m < 64; m <<= 1) {
        s += __shfl_xor(s, m);
        s2 += __shfl_xor(s2, m);
    }
    __shared__ float red[8];
    int wv = t >> 6, ln = t & 63;
    if (ln == 0) { red[wv] = s; red[wv + 4] = s2; }
    __syncthreads();
    s = red[0] + red[1] + red[2] + red[3];
    s2 = red[4] + red[5] + red[6] + red[7];
    float mu = s * (1.0f / N_EMBED);
    float var = s2 * (1.0f / N_EMBED) - mu * mu;
    float r = rsqrtf(var + 1e-5f);
    float4 wv4 = reinterpret_cast<const float4*>(w)[t];
    float4 bv4 = reinterpret_cast<const float4*>(b)[t];
    ushort4 o;
    o.x = f2bf((v.x - mu) * r * wv4.x + bv4.x);
    o.y = f2bf((v.y - mu) * r * wv4.y + bv4.y);
    o.z = f2bf((v.z - mu) * r * wv4.z + bv4.z);
    o.w = f2bf((v.w - mu) * r * wv4.w + bv4.w);
    *reinterpret_cast<ushort4*>(out + (size_t)row * N_EMBED + t * 4) = o;
}

// ---------------------------------------------------------------------------
// bf16 GEMM: C[M][N] = A[M][K] @ BT[N][K]^T + bias. m97 structure + XCD swizzle.
// ---------------------------------------------------------------------------
template <int EPI>
__global__ __launch_bounds__(256) void gemm_kernel(
    const unsigned short* __restrict__ A,   // [M][K] bf16
    const unsigned short* __restrict__ BT,  // [N][K] bf16
    const float* __restrict__ bias,         // [N]
    const float* __restrict__ resid,        // [M][N] fp32 or nullptr
    float* __restrict__ outf,               // [M][N] fp32 (EPI 1)
    unsigned short* __restrict__ outb,      // [M][N] bf16 (EPI 0,2)
    int M, int N, int K) {
    __shared__ __align__(16) unsigned short As[128 * 32];
    __shared__ __align__(16) unsigned short Bs[128 * 32];
    int nbn = N >> 7;
    int nwg = gridDim.x;
    int orig = blockIdx.x;
    int swz = (orig & 7) * (nwg >> 3) + (orig >> 3);
    int bm = swz / nbn, bn = swz % nbn;
    int t = threadIdx.x;
    int lane = t & 63, wv = t >> 6;
    int wm = wv >> 1, wn = wv & 1;
    int mr = lane & 15, kg = lane >> 4;

    f32x4 acc[4][4];
#pragma unroll
    for (int i = 0; i < 4; i++)
#pragma unroll
        for (int j = 0; j < 4; j++) acc[i][j] = (f32x4){0.f, 0.f, 0.f, 0.f};

    int srow = t >> 2, sq = t & 3;
    const unsigned short* gA1 = A + (size_t)(bm * 128 + srow) * K + sq * 8;
    const unsigned short* gA2 = gA1 + (size_t)64 * K;
    const unsigned short* gB1 = BT + (size_t)(bn * 128 + srow) * K + sq * 8;
    const unsigned short* gB2 = gB1 + (size_t)64 * K;
    int w512 = (t >> 6) * 512;

    for (int k0 = 0; k0 < K; k0 += 32) {
        __syncthreads();
        gll16(gA1 + k0, As + w512);
        gll16(gA2 + k0, As + 2048 + w512);
        gll16(gB1 + k0, Bs + w512);
        gll16(gB2 + k0, Bs + 2048 + w512);
        __syncthreads();
        bf16x8 af[4], bfr[4];
#pragma unroll
        for (int i = 0; i < 4; i++)
            af[i] = *reinterpret_cast<const bf16x8*>(&As[(wm * 64 + i * 16 + mr) * 32 + kg * 8]);
#pragma unroll
        for (int j = 0; j < 4; j++)
            bfr[j] = *reinterpret_cast<const bf16x8*>(&Bs[(wn * 64 + j * 16 + mr) * 32 + kg * 8]);
#pragma unroll
        for (int i = 0; i < 4; i++)
#pragma unroll
            for (int j = 0; j < 4; j++)
                acc[i][j] = __builtin_amdgcn_mfma_f32_16x16x32_bf16(af[i], bfr[j], acc[i][j], 0, 0, 0);
    }

#pragma unroll
    for (int i = 0; i < 4; i++)
#pragma unroll
        for (int j = 0; j < 4; j++) {
            int n = bn * 128 + wn * 64 + j * 16 + mr;
            float bs = bias[n];
#pragma unroll
            for (int r = 0; r < 4; r++) {
                int m = bm * 128 + wm * 64 + i * 16 + kg * 4 + r;
                size_t idx = (size_t)m * N + n;
                float v = acc[i][j][r] + bs;
                if (EPI == 0) {
                    outb[idx] = f2bf(v);
                } else if (EPI == 1) {
                    outf[idx] = v + resid[idx];
                } else {
                    float g = 0.5f * v * (1.0f + erff(v * 0.70710678118f));
                    outb[idx] = f2bf(g);
                }
            }
        }
}

// ---------------------------------------------------------------------------
// Flash-style causal attention. Barrier-free, per-wave independent.
// 2048 blocks = (bh major, qt minor). 4 waves, each owns 16 q rows.
// K double-buffered in REGISTERS (prefetch tile t+1 while computing t);
// V fragments loaded before softmax (latency covered by softmax VALU).
// K/V come from packed per-tile 8KB chunks (kpk/vpk) -> dense L1/L2 streams.
// LDS: only the 8KB wave-local P bounce.
// ---------------------------------------------------------------------------
__global__ __launch_bounds__(256) void attn_kernel(
    const unsigned short* __restrict__ qkv,
    const unsigned short* __restrict__ kpk,
    const unsigned short* __restrict__ vpk,
    unsigned short* __restrict__ ctx) {
    __shared__ __align__(16) unsigned short PL[4096];
    int t = threadIdx.x, lane = t & 63, wv = t >> 6;
    int mr = lane & 15, kg = lane >> 4;
    const float SCL = 0.18033688011112042f;  // 0.125 * log2(e)

    int wid = blockIdx.x;
    int bh = wid >> 5, qt = wid & 31;
    int h = bh & 15, b = bh >> 4;
    int qbase = qt * 64 + wv * 16;

    const unsigned short* qp = qkv + (size_t)(b * TT) * QKV_LD + h * HD;
    const unsigned short* kb = kpk + (size_t)bh * 32 * 4096;
    const unsigned short* vb = vpk + (size_t)bh * 32 * 4096;

    bf16x8 aq[2];
#pragma unroll
    for (int c = 0; c < 2; c++)
        aq[c] = *reinterpret_cast<const bf16x8*>(
            qp + (size_t)(qbase + mr) * QKV_LD + c * 32 + kg * 8);

    f32x4 Oa[4];
#pragma unroll
    for (int jd = 0; jd < 4; jd++) Oa[jd] = (f32x4){0.f, 0.f, 0.f, 0.f};
    float mrow[4] = {-3.0e38f, -3.0e38f, -3.0e38f, -3.0e38f};
    float lrow[4] = {0.f, 0.f, 0.f, 0.f};

    auto loadK = [&](bf16x8 (&Kf)[4][2], int tile) {
        const unsigned short* kt = kb + (size_t)tile * 4096;
#pragma unroll
        for (int j = 0; j < 4; j++)
#pragma unroll
            for (int c = 0; c < 2; c++)
                Kf[j][c] = *reinterpret_cast<const bf16x8*>(
                    kt + (j * 16 + mr) * 64 + c * 32 + kg * 8);
    };

    auto compute = [&](bf16x8 (&Kf)[4][2], int tile) {
        int kv0 = tile * 64;
        // S = Q @ K^T
        f32x4 sf[4];
#pragma unroll
        for (int j = 0; j < 4; j++) {
            f32x4 s = (f32x4){0.f, 0.f, 0.f, 0.f};
#pragma unroll
            for (int c = 0; c < 2; c++)
                s = __builtin_amdgcn_mfma_f32_16x16x32_bf16(aq[c], Kf[j][c], s, 0, 0, 0);
            sf[j] = s;
        }
        // V fragments now — softmax VALU below covers their latency
        bf16x8 vf[4][2];
        const unsigned short* vtile = vb + (size_t)tile * 4096;
#pragma unroll
        for (int jd = 0; jd < 4; jd++)
#pragma unroll
            for (int c = 0; c < 2; c++)
                vf[jd][c] = *reinterpret_cast<const bf16x8*>(
                    vtile + (jd * 16 + mr) * 64 + c * 32 + kg * 8);

        // scale (log2 domain) + causal mask (diagonal tile only) + online softmax
        float tmax[4];
        if (tile == qt) {
#pragma unroll
            for (int r = 0; r < 4; r++) {
                int qrow = qbase + kg * 4 + r;
                float mx = -3.0e38f;
#pragma unroll
                for (int j = 0; j < 4; j++) {
                    int kc = kv0 + j * 16 + mr;
                    float sv = sf[j][r] * SCL;
                    if (kc > qrow) sv = -3.0e38f;
                    sf[j][r] = sv;
                    mx = fmaxf(mx, sv);
                }
                tmax[r] = mx;
            }
        } else {
#pragma unroll
            for (int r = 0; r < 4; r++) {
                float mx = -3.0e38f;
#pragma unroll
                for (int j = 0; j < 4; j++) {
                    float sv = sf[j][r] * SCL;
                    sf[j][r] = sv;
                    mx = fmaxf(mx, sv);
                }
                tmax[r] = mx;
            }
        }
#pragma unroll
        for (int r = 0; r < 4; r++) {
#pragma unroll
            for (int m = 1; m < 16; m <<= 1) tmax[r] = fmaxf(tmax[r], __shfl_xor(tmax[r], m));
        }
#pragma unroll
        for (int r = 0; r < 4; r++) {
            float mn = fmaxf(mrow[r], tmax[r]);
            float alpha = __builtin_amdgcn_exp2f(mrow[r] - mn);
            mrow[r] = mn;
            lrow[r] *= alpha;
#pragma unroll
            for (int jd = 0; jd < 4; jd++) Oa[jd][r] *= alpha;
        }
        float rsum[4] = {0.f, 0.f, 0.f, 0.f};
#pragma unroll
        for (int j = 0; j < 4; j++)
#pragma unroll
            for (int r = 0; r < 4; r++) {
                float p = __builtin_amdgcn_exp2f(sf[j][r] - mrow[r]);
                sf[j][r] = p;
                rsum[r] += p;
            }
#pragma unroll
        for (int r = 0; r < 4; r++) {
#pragma unroll
            for (int m = 1; m < 16; m <<= 1) rsum[r] += __shfl_xor(rsum[r], m);
            lrow[r] += rsum[r];
        }

        // P -> LDS (wave-local rows, XOR-swizzled) -> A fragments
#pragma unroll
        for (int r = 0; r < 4; r++) {
            int qrow = wv * 16 + kg * 4 + r;
            int base = qrow * 64;
            int sw = (qrow & 7) << 3;
#pragma unroll
            for (int j = 0; j < 4; j++)
                PL[(base + j * 16 + mr) ^ sw] = f2bf(sf[j][r]);
        }
        const int csw = mr & 7;
        // O += P @ V
#pragma unroll
        for (int c = 0; c < 2; c++) {
            bf16x8 pa = *reinterpret_cast<const bf16x8*>(
                &PL[(wv * 16 + mr) * 64 + ((4 * c + kg) ^ csw) * 8]);
#pragma unroll
            for (int jd = 0; jd < 4; jd++)
                Oa[jd] = __builtin_amdgcn_mfma_f32_16x16x32_bf16(pa, vf[jd][c], Oa[jd], 0, 0, 0);
        }
    };

    // register-double-buffered K pipeline (named sets; no runtime reg indexing)
    bf16x8 K0[4][2], K1[4][2];
    loadK(K0, 0);
    int tile = 0;
    while (true) {
        if (tile + 1 <= qt) loadK(K1, tile + 1);
        compute(K0, tile);
        if (++tile > qt) break;
        if (tile + 1 <= qt) loadK(K0, tile + 1);
        compute(K1, tile);
        if (++tile > qt) break;
    }

    // epilogue: ctx = O / l
    float inv[4];
#pragma unroll
    for (int r = 0; r < 4; r++) inv[r] = 1.0f / lrow[r];
#pragma unroll
    for (int jd = 0; jd < 4; jd++)
#pragma unroll
        for (int r = 0; r < 4; r++) {
            int q = qbase + kg * 4 + r;
            ctx[(size_t)(b * TT + q) * N_EMBED + h * HD + jd * 16 + mr] =
                f2bf(Oa[jd][r] * inv[r]);
        }
}

// ---------------------------------------------------------------------------
extern "C" void kernel_launch(void* const* d_in, const int* in_sizes, int n_in,
                              void* d_out, int out_size, void* d_ws, size_t ws_size,
                              hipStream_t stream) {
    const float* x      = (const float*)d_in[0];
    const float* ln1_w  = (const float*)d_in[1];
    const float* ln1_b  = (const float*)d_in[2];
    const float* w_qkv  = (const float*)d_in[3];
    const float* b_qkv  = (const float*)d_in[4];
    const float* w_o    = (const float*)d_in[5];
    const float* b_o    = (const float*)d_in[6];
    const float* ln2_w  = (const float*)d_in[7];
    const float* ln2_b  = (const float*)d_in[8];
    const float* w_fc   = (const float*)d_in[9];
    const float* b_fc   = (const float*)d_in[10];
    const float* w_proj = (const float*)d_in[11];
    const float* b_proj = (const float*)d_in[12];
    float* out = (float*)d_out;

    char* ws = (char*)d_ws;
    size_t off = 0;
    auto alloc = [&](size_t bytes) -> void* {
        void* p = ws + off;
        off += (bytes + 255) & ~(size_t)255;
        return p;
    };
    unsigned short* wqkv_t  = (unsigned short*)alloc((size_t)3072 * 1024 * 2);
    unsigned short* wo_t    = (unsigned short*)alloc((size_t)1024 * 1024 * 2);
    unsigned short* wfc_t   = (unsigned short*)alloc((size_t)4096 * 1024 * 2);
    unsigned short* wproj_t = (unsigned short*)alloc((size_t)1024 * 4096 * 2);
    unsigned short* lnb     = (unsigned short*)alloc((size_t)NTOK * 1024 * 2);
    float*          x1      = (float*)alloc((size_t)NTOK * 1024 * 4);
    unsigned short* qkv     = (unsigned short*)alloc((size_t)NTOK * 3072 * 2);
    unsigned short* ctxb    = (unsigned short*)alloc((size_t)NTOK * 1024 * 2);
    unsigned short* hbuf    = qkv;                  // overlays qkv (dead after attn)
    unsigned short* kpk     = (unsigned short*)x1;  // overlays x1 (x1 written after attn)
    unsigned short* vpk     = kpk + (size_t)64 * 32 * 4096;

    dim3 tb32(32, 8);
    transpose_bf16_kernel<<<dim3(3072 / 32, 1024 / 32), tb32, 0, stream>>>(w_qkv, wqkv_t, 1024, 3072);
    transpose_bf16_kernel<<<dim3(1024 / 32, 1024 / 32), tb32, 0, stream>>>(w_o, wo_t, 1024, 1024);
    transpose_bf16_kernel<<<dim3(4096 / 32, 1024 / 32), tb32, 0, stream>>>(w_fc, wfc_t, 1024, 4096);
    transpose_bf16_kernel<<<dim3(1024 / 32, 4096 / 32), tb32, 0, stream>>>(w_proj, wproj_t, 4096, 1024);

    // ln1(x) -> lnb
    ln_kernel<<<NTOK, 256, 0, stream>>>(x, ln1_w, ln1_b, lnb);
    // qkv = lnb @ w_qkv + b_qkv
    gemm_kernel<0><<<(NTOK / 128) * (3072 / 128), 256, 0, stream>>>(
        lnb, wqkv_t, b_qkv, nullptr, nullptr, qkv, NTOK, 3072, 1024);
    // pack K/V into per-tile chunks
    pack_kv_kernel<<<64 * 32, 256, 0, stream>>>(qkv, kpk, vpk);
    // attention -> ctx
    attn_kernel<<<2048, 256, 0, stream>>>(qkv, kpk, vpk, ctxb);
    // x1 = ctx @ w_o + b_o + x   (x1 overwrites kpk/vpk — dead now)
    gemm_kernel<1><<<(NTOK / 128) * (1024 / 128), 256, 0, stream>>>(
        ctxb, wo_t, b_o, x, x1, nullptr, NTOK, 1024, 1024);
    // ln2(x1) -> lnb
    ln_kernel<<<NTOK, 256, 0, stream>>>(x1, ln2_w, ln2_b, lnb);
    // h = gelu(lnb @ w_fc + b_fc)
    gemm_kernel<2><<<(NTOK / 128) * (4096 / 128), 256, 0, stream>>>(
        lnb, wfc_t, b_fc, nullptr, nullptr, hbuf, NTOK, 4096, 1024);
    // out = h @ w_proj + b_proj + x1
    gemm_kernel<1><<<(NTOK / 128) * (1024 / 128), 256, 0, stream>>>(
        hbuf, wproj_t, b_proj, x1, out, nullptr, NTOK, 1024, 4096);
}

// Round 5
// 550.629 us; speedup vs baseline: 1.4627x; 1.4627x over previous
//
#include <hip/hip_runtime.h>
#include <hip/hip_bf16.h>
#include <math.h>

#define N_EMBED 1024
#define N_HEAD 16
#define HD 64
#define BB 4
#define TT 2048
#define NTOK (BB * TT)        // 8192 rows
#define QKV_LD (3 * N_EMBED)  // 3072

typedef __bf16 bf16x8 __attribute__((ext_vector_type(8)));
typedef float f32x4 __attribute__((ext_vector_type(4)));

__device__ __forceinline__ unsigned short f2bf(float f) {
    __hip_bfloat16 h = __float2bfloat16(f);
    return __builtin_bit_cast(unsigned short, h);
}

// async global->LDS, 16B per lane. LDS dest = wave-uniform base + lane*16.
__device__ __forceinline__ void gll16(const unsigned short* g, unsigned short* l) {
    __builtin_amdgcn_global_load_lds(
        (const __attribute__((address_space(1))) void*)g,
        (__attribute__((address_space(3))) void*)l,
        16, 0, 0);
}

// ---------------------------------------------------------------------------
// Weight transpose + fp32 -> bf16 convert:  in [K][N] fp32  ->  out [N][K] bf16
// ---------------------------------------------------------------------------
__global__ __launch_bounds__(256) void transpose_bf16_kernel(
    const float* __restrict__ in, unsigned short* __restrict__ out, int K, int N) {
    __shared__ float tile[32][33];
    int bx = blockIdx.x * 32;  // n base
    int by = blockIdx.y * 32;  // k base
    int tx = threadIdx.x, ty = threadIdx.y;
#pragma unroll
    for (int i = ty; i < 32; i += 8)
        tile[i][tx] = in[(size_t)(by + i) * N + bx + tx];
    __syncthreads();
#pragma unroll
    for (int i = ty; i < 32; i += 8)
        out[(size_t)(bx + i) * K + by + tx] = f2bf(tile[tx][i]);
}

// ---------------------------------------------------------------------------
// V transpose: qkv [B*T][3072] (v at col 2048+h*64) -> vt [b*16+h][64][2048]
// ---------------------------------------------------------------------------
__global__ __launch_bounds__(256) void transpose_v_kernel(
    const unsigned short* __restrict__ qkv, unsigned short* __restrict__ vt) {
    __shared__ unsigned short tile[32][33];
    int z = blockIdx.z;
    int b = z >> 4, h = z & 15;
    int t0 = blockIdx.x * 32, d0 = blockIdx.y * 32;
    int tx = threadIdx.x, ty = threadIdx.y;
    const unsigned short* src = qkv + (size_t)(b * TT) * QKV_LD + 2 * N_EMBED + h * HD;
#pragma unroll
    for (int i = ty; i < 32; i += 8)
        tile[i][tx] = src[(size_t)(t0 + i) * QKV_LD + d0 + tx];
    __syncthreads();
    unsigned short* dst = vt + (size_t)z * HD * TT;
#pragma unroll
    for (int i = ty; i < 32; i += 8)
        dst[(size_t)(d0 + i) * TT + t0 + tx] = tile[tx][i];
}

// ---------------------------------------------------------------------------
// Row LayerNorm: fp32 in [rows][1024] -> bf16 out
// ---------------------------------------------------------------------------
__global__ __launch_bounds__(256) void ln_kernel(
    const float* __restrict__ x, const float* __restrict__ w,
    const float* __restrict__ b, unsigned short* __restrict__ out) {
    int row = blockIdx.x;
    int t = threadIdx.x;
    const float* xr = x + (size_t)row * N_EMBED;
    float4 v = reinterpret_cast<const float4*>(xr)[t];
    float s = v.x + v.y + v.z + v.w;
    float s2 = v.x * v.x + v.y * v.y + v.z * v.z + v.w * v.w;
#pragma unroll
    for (int m = 1; m < 64; m <<= 1) {
        s += __shfl_xor(s, m);
        s2 += __shfl_xor(s2, m);
    }
    __shared__ float red[8];
    int wv = t >> 6, ln = t & 63;
    if (ln == 0) { red[wv] = s; red[wv + 4] = s2; }
    __syncthreads();
    s = red[0] + red[1] + red[2] + red[3];
    s2 = red[4] + red[5] + red[6] + red[7];
    float mu = s * (1.0f / N_EMBED);
    float var = s2 * (1.0f / N_EMBED) - mu * mu;
    float r = rsqrtf(var + 1e-5f);
    float4 wv4 = reinterpret_cast<const float4*>(w)[t];
    float4 bv4 = reinterpret_cast<const float4*>(b)[t];
    ushort4 o;
    o.x = f2bf((v.x - mu) * r * wv4.x + bv4.x);
    o.y = f2bf((v.y - mu) * r * wv4.y + bv4.y);
    o.z = f2bf((v.z - mu) * r * wv4.z + bv4.z);
    o.w = f2bf((v.w - mu) * r * wv4.w + bv4.w);
    *reinterpret_cast<ushort4*>(out + (size_t)row * N_EMBED + t * 4) = o;
}

// ---------------------------------------------------------------------------
// bf16 GEMM: C[M][N] = A[M][K] @ BT[N][K]^T + bias. m97 structure + XCD swizzle.
// ---------------------------------------------------------------------------
template <int EPI>
__global__ __launch_bounds__(256) void gemm_kernel(
    const unsigned short* __restrict__ A,   // [M][K] bf16
    const unsigned short* __restrict__ BT,  // [N][K] bf16
    const float* __restrict__ bias,         // [N]
    const float* __restrict__ resid,        // [M][N] fp32 or nullptr
    float* __restrict__ outf,               // [M][N] fp32 (EPI 1)
    unsigned short* __restrict__ outb,      // [M][N] bf16 (EPI 0,2)
    int M, int N, int K) {
    __shared__ __align__(16) unsigned short As[128 * 32];
    __shared__ __align__(16) unsigned short Bs[128 * 32];
    int nbn = N >> 7;
    int nwg = gridDim.x;
    int orig = blockIdx.x;
    int swz = (orig & 7) * (nwg >> 3) + (orig >> 3);
    int bm = swz / nbn, bn = swz % nbn;
    int t = threadIdx.x;
    int lane = t & 63, wv = t >> 6;
    int wm = wv >> 1, wn = wv & 1;
    int mr = lane & 15, kg = lane >> 4;

    f32x4 acc[4][4];
#pragma unroll
    for (int i = 0; i < 4; i++)
#pragma unroll
        for (int j = 0; j < 4; j++) acc[i][j] = (f32x4){0.f, 0.f, 0.f, 0.f};

    int srow = t >> 2, sq = t & 3;
    const unsigned short* gA1 = A + (size_t)(bm * 128 + srow) * K + sq * 8;
    const unsigned short* gA2 = gA1 + (size_t)64 * K;
    const unsigned short* gB1 = BT + (size_t)(bn * 128 + srow) * K + sq * 8;
    const unsigned short* gB2 = gB1 + (size_t)64 * K;
    int w512 = (t >> 6) * 512;

    for (int k0 = 0; k0 < K; k0 += 32) {
        __syncthreads();
        gll16(gA1 + k0, As + w512);
        gll16(gA2 + k0, As + 2048 + w512);
        gll16(gB1 + k0, Bs + w512);
        gll16(gB2 + k0, Bs + 2048 + w512);
        __syncthreads();
        bf16x8 af[4], bfr[4];
#pragma unroll
        for (int i = 0; i < 4; i++)
            af[i] = *reinterpret_cast<const bf16x8*>(&As[(wm * 64 + i * 16 + mr) * 32 + kg * 8]);
#pragma unroll
        for (int j = 0; j < 4; j++)
            bfr[j] = *reinterpret_cast<const bf16x8*>(&Bs[(wn * 64 + j * 16 + mr) * 32 + kg * 8]);
#pragma unroll
        for (int i = 0; i < 4; i++)
#pragma unroll
            for (int j = 0; j < 4; j++)
                acc[i][j] = __builtin_amdgcn_mfma_f32_16x16x32_bf16(af[i], bfr[j], acc[i][j], 0, 0, 0);
    }

#pragma unroll
    for (int i = 0; i < 4; i++)
#pragma unroll
        for (int j = 0; j < 4; j++) {
            int n = bn * 128 + wn * 64 + j * 16 + mr;
            float bs = bias[n];
#pragma unroll
            for (int r = 0; r < 4; r++) {
                int m = bm * 128 + wm * 64 + i * 16 + kg * 4 + r;
                size_t idx = (size_t)m * N + n;
                float v = acc[i][j][r] + bs;
                if (EPI == 0) {
                    outb[idx] = f2bf(v);
                } else if (EPI == 1) {
                    outf[idx] = v + resid[idx];
                } else {
                    float g = 0.5f * v * (1.0f + erff(v * 0.70710678118f));
                    outb[idx] = f2bf(g);
                }
            }
        }
}

// ---------------------------------------------------------------------------
// Flash-style causal attention. 512 blocks, 4 waves x 32 q-rows = 128-row
// Q tiles; qt in [0,16); block handles items {qt=qp, qt=15-qp} -> exactly 34
// KV-tile iterations each. K/V staged in triple-buffered LDS via
// global_load_lds (source-side XOR swizzle), counted vmcnt(4) + raw s_barrier
// so next-tile DMAs stay in flight across the barrier (T3/T4).
// LDS: K 3x8KB + V 3x8KB + P 16KB = 64KB -> 2 blocks/CU.
// ---------------------------------------------------------------------------
__global__ __launch_bounds__(256) void attn_kernel(
    const unsigned short* __restrict__ qkv,
    const unsigned short* __restrict__ vt,
    unsigned short* __restrict__ ctx) {
    __shared__ __align__(16) unsigned short Kb[3][4096];
    __shared__ __align__(16) unsigned short Vb[3][4096];
    __shared__ __align__(16) unsigned short PL[8192];  // 128 rows x 64, wave-local
    const float SCL = 0.18033688011112042f;  // 0.125 * log2(e)
    int t = threadIdx.x, lane = t & 63, wv = t >> 6;
    int mr = lane & 15, kg = lane >> 4;

    int wid = blockIdx.x;          // bh*8 + qp
    int bh = wid >> 3, qp2 = wid & 7;
    int h = bh & 15, b = bh >> 4;

    const unsigned short* qptr = qkv + (size_t)(b * TT) * QKV_LD + h * HD;
    const unsigned short* kp = qptr + N_EMBED;
    const unsigned short* vtp = vt + (size_t)bh * HD * TT;

    // staging geometry: call i covers 16B-chunks i*256 + wv*64 + lane
    int srow[2], scol[2], sbase[2];
#pragma unroll
    for (int i = 0; i < 2; i++) {
        int L = i * 256 + wv * 64 + lane;
        int row = L >> 3, slot = L & 7;
        srow[i] = row;
        scol[i] = (slot ^ (row & 7)) * 8;    // pre-swizzled global source chunk
        sbase[i] = (i * 256 + wv * 64) * 8;  // wave-uniform LDS base (ushorts)
    }
    const int csw = mr & 7;  // read-side chunk XOR

    auto stage = [&](int tile, int bi) {
        int kv0 = tile * 64;
#pragma unroll
        for (int i = 0; i < 2; i++) {
            gll16(kp + (size_t)(kv0 + srow[i]) * QKV_LD + scol[i], &Kb[bi][sbase[i]]);
            gll16(vtp + (size_t)srow[i] * TT + kv0 + scol[i], &Vb[bi][sbase[i]]);
        }
    };

    for (int item = 0; item < 2; ++item) {
        int qt = (item == 0) ? qp2 : 15 - qp2;
        int ntiles = 2 * qt + 2;
        int qbase = qt * 128 + wv * 32;

        bf16x8 aq[2][2];
#pragma unroll
        for (int f = 0; f < 2; f++)
#pragma unroll
            for (int c = 0; c < 2; c++)
                aq[f][c] = *reinterpret_cast<const bf16x8*>(
                    qptr + (size_t)(qbase + f * 16 + mr) * QKV_LD + c * 32 + kg * 8);

        f32x4 Oa[2][4];
#pragma unroll
        for (int f = 0; f < 2; f++)
#pragma unroll
            for (int jd = 0; jd < 4; jd++) Oa[f][jd] = (f32x4){0.f, 0.f, 0.f, 0.f};
        float mrow[2][4], lrow[2][4];
#pragma unroll
        for (int f = 0; f < 2; f++)
#pragma unroll
            for (int r = 0; r < 4; r++) { mrow[f][r] = -3.0e38f; lrow[f][r] = 0.f; }

        // prologue: two tiles in flight
        stage(0, 0);
        stage(1, 1);

        for (int tl = 0; tl < ntiles; ++tl) {
            // per-wave certified: my quarter of tile tl has landed; after the
            // barrier, everyone's quarter has landed. tl+1/tl+2 stay in flight.
            if (tl + 1 < ntiles) {
                asm volatile("s_waitcnt vmcnt(4)" ::: "memory");
            } else {
                asm volatile("s_waitcnt vmcnt(0)" ::: "memory");
            }
            __builtin_amdgcn_s_barrier();
            int t2 = tl + 2;
            if (t2 < ntiles) stage(t2, t2 % 3);

            int bi = tl % 3;
            int kv0 = tl * 64;
            const unsigned short* Kt = Kb[bi];
            const unsigned short* Vt = Vb[bi];

            // S = Q @ K^T : 2 q-frags x 4 kv-frags
            f32x4 sf[2][4];
#pragma unroll
            for (int j = 0; j < 4; j++) {
                int rl = j * 16 + mr;
                bf16x8 bk0 = *reinterpret_cast<const bf16x8*>(&Kt[rl * 64 + (kg ^ csw) * 8]);
                bf16x8 bk1 = *reinterpret_cast<const bf16x8*>(&Kt[rl * 64 + ((4 + kg) ^ csw) * 8]);
#pragma unroll
                for (int f = 0; f < 2; f++) {
                    f32x4 s = (f32x4){0.f, 0.f, 0.f, 0.f};
                    s = __builtin_amdgcn_mfma_f32_16x16x32_bf16(aq[f][0], bk0, s, 0, 0, 0);
                    s = __builtin_amdgcn_mfma_f32_16x16x32_bf16(aq[f][1], bk1, s, 0, 0, 0);
                    sf[f][j] = s;
                }
            }

            bool dmask = (tl >= 2 * qt);  // only last two tiles touch the diagonal
#pragma unroll
            for (int f = 0; f < 2; f++) {
                float tmax[4];
#pragma unroll
                for (int r = 0; r < 4; r++) {
                    int qrow = qbase + f * 16 + kg * 4 + r;
                    float mx = -3.0e38f;
#pragma unroll
                    for (int j = 0; j < 4; j++) {
                        float sv = sf[f][j][r] * SCL;
                        if (dmask && (kv0 + j * 16 + mr > qrow)) sv = -3.0e38f;
                        sf[f][j][r] = sv;
                        mx = fmaxf(mx, sv);
                    }
                    tmax[r] = mx;
                }
#pragma unroll
                for (int r = 0; r < 4; r++) {
#pragma unroll
                    for (int m = 1; m < 16; m <<= 1)
                        tmax[r] = fmaxf(tmax[r], __shfl_xor(tmax[r], m));
                    float mn = fmaxf(mrow[f][r], tmax[r]);
                    float al = __builtin_amdgcn_exp2f(mrow[f][r] - mn);
                    mrow[f][r] = mn;
                    lrow[f][r] *= al;
#pragma unroll
                    for (int jd = 0; jd < 4; jd++) Oa[f][jd][r] *= al;
                }
                float rsum[4] = {0.f, 0.f, 0.f, 0.f};
#pragma unroll
                for (int j = 0; j < 4; j++)
#pragma unroll
                    for (int r = 0; r < 4; r++) {
                        float p = __builtin_amdgcn_exp2f(sf[f][j][r] - mrow[f][r]);
                        sf[f][j][r] = p;
                        rsum[r] += p;
                    }
#pragma unroll
                for (int r = 0; r < 4; r++) {
#pragma unroll
                    for (int m = 1; m < 16; m <<= 1) rsum[r] += __shfl_xor(rsum[r], m);
                    lrow[f][r] += rsum[r];
                }
                // P -> LDS (wave-local rows, XOR-swizzled)
#pragma unroll
                for (int r = 0; r < 4; r++) {
                    int rowL = wv * 32 + f * 16 + kg * 4 + r;
                    int base = rowL * 64;
                    int sw = (rowL & 7) << 3;
#pragma unroll
                    for (int j = 0; j < 4; j++)
                        PL[(base + j * 16 + mr) ^ sw] = f2bf(sf[f][j][r]);
                }
            }

            // O += P @ V
#pragma unroll
            for (int c = 0; c < 2; c++) {
                int ch = ((4 * c + kg) ^ csw) * 8;
                bf16x8 pa0 = *reinterpret_cast<const bf16x8*>(&PL[(wv * 32 + mr) * 64 + ch]);
                bf16x8 pa1 = *reinterpret_cast<const bf16x8*>(&PL[(wv * 32 + 16 + mr) * 64 + ch]);
#pragma unroll
                for (int jd = 0; jd < 4; jd++) {
                    bf16x8 vf = *reinterpret_cast<const bf16x8*>(&Vt[(jd * 16 + mr) * 64 + ch]);
                    Oa[0][jd] = __builtin_amdgcn_mfma_f32_16x16x32_bf16(pa0, vf, Oa[0][jd], 0, 0, 0);
                    Oa[1][jd] = __builtin_amdgcn_mfma_f32_16x16x32_bf16(pa1, vf, Oa[1][jd], 0, 0, 0);
                }
            }
        }

        // epilogue: ctx = O / l
        float inv[2][4];
#pragma unroll
        for (int f = 0; f < 2; f++)
#pragma unroll
            for (int r = 0; r < 4; r++) inv[f][r] = 1.0f / lrow[f][r];
#pragma unroll
        for (int f = 0; f < 2; f++)
#pragma unroll
            for (int jd = 0; jd < 4; jd++)
#pragma unroll
                for (int r = 0; r < 4; r++) {
                    int q = qbase + f * 16 + kg * 4 + r;
                    ctx[(size_t)(b * TT + q) * N_EMBED + h * HD + jd * 16 + mr] =
                        f2bf(Oa[f][jd][r] * inv[f][r]);
                }
        __syncthreads();  // buffers free before next item's prologue staging
    }
}

// ---------------------------------------------------------------------------
extern "C" void kernel_launch(void* const* d_in, const int* in_sizes, int n_in,
                              void* d_out, int out_size, void* d_ws, size_t ws_size,
                              hipStream_t stream) {
    const float* x      = (const float*)d_in[0];
    const float* ln1_w  = (const float*)d_in[1];
    const float* ln1_b  = (const float*)d_in[2];
    const float* w_qkv  = (const float*)d_in[3];
    const float* b_qkv  = (const float*)d_in[4];
    const float* w_o    = (const float*)d_in[5];
    const float* b_o    = (const float*)d_in[6];
    const float* ln2_w  = (const float*)d_in[7];
    const float* ln2_b  = (const float*)d_in[8];
    const float* w_fc   = (const float*)d_in[9];
    const float* b_fc   = (const float*)d_in[10];
    const float* w_proj = (const float*)d_in[11];
    const float* b_proj = (const float*)d_in[12];
    float* out = (float*)d_out;

    char* ws = (char*)d_ws;
    size_t off = 0;
    auto alloc = [&](size_t bytes) -> void* {
        void* p = ws + off;
        off += (bytes + 255) & ~(size_t)255;
        return p;
    };
    unsigned short* wqkv_t  = (unsigned short*)alloc((size_t)3072 * 1024 * 2);
    unsigned short* wo_t    = (unsigned short*)alloc((size_t)1024 * 1024 * 2);
    unsigned short* wfc_t   = (unsigned short*)alloc((size_t)4096 * 1024 * 2);
    unsigned short* wproj_t = (unsigned short*)alloc((size_t)1024 * 4096 * 2);
    unsigned short* lnb     = (unsigned short*)alloc((size_t)NTOK * 1024 * 2);
    float*          x1      = (float*)alloc((size_t)NTOK * 1024 * 4);
    unsigned short* qkv     = (unsigned short*)alloc((size_t)NTOK * 3072 * 2);
    unsigned short* ctxb    = (unsigned short*)alloc((size_t)NTOK * 1024 * 2);
    unsigned short* hbuf    = qkv;                 // overlays qkv (dead after attn)
    unsigned short* vt      = (unsigned short*)x1; // overlays x1 (written after attn)

    dim3 tb32(32, 8);
    transpose_bf16_kernel<<<dim3(3072 / 32, 1024 / 32), tb32, 0, stream>>>(w_qkv, wqkv_t, 1024, 3072);
    transpose_bf16_kernel<<<dim3(1024 / 32, 1024 / 32), tb32, 0, stream>>>(w_o, wo_t, 1024, 1024);
    transpose_bf16_kernel<<<dim3(4096 / 32, 1024 / 32), tb32, 0, stream>>>(w_fc, wfc_t, 1024, 4096);
    transpose_bf16_kernel<<<dim3(1024 / 32, 4096 / 32), tb32, 0, stream>>>(w_proj, wproj_t, 4096, 1024);

    // ln1(x) -> lnb
    ln_kernel<<<NTOK, 256, 0, stream>>>(x, ln1_w, ln1_b, lnb);
    // qkv = lnb @ w_qkv + b_qkv
    gemm_kernel<0><<<(NTOK / 128) * (3072 / 128), 256, 0, stream>>>(
        lnb, wqkv_t, b_qkv, nullptr, nullptr, qkv, NTOK, 3072, 1024);
    // V transpose -> vt
    transpose_v_kernel<<<dim3(TT / 32, HD / 32, BB * N_HEAD), tb32, 0, stream>>>(qkv, vt);
    // attention -> ctx  (512 blocks, LPT-paired, 34 tiles each)
    attn_kernel<<<512, 256, 0, stream>>>(qkv, vt, ctxb);
    // x1 = ctx @ w_o + b_o + x   (x1 overwrites vt region — vt dead now)
    gemm_kernel<1><<<(NTOK / 128) * (1024 / 128), 256, 0, stream>>>(
        ctxb, wo_t, b_o, x, x1, nullptr, NTOK, 1024, 1024);
    // ln2(x1) -> lnb
    ln_kernel<<<NTOK, 256, 0, stream>>>(x1, ln2_w, ln2_b, lnb);
    // h = gelu(lnb @ w_fc + b_fc)
    gemm_kernel<2><<<(NTOK / 128) * (4096 / 128), 256, 0, stream>>>(
        lnb, wfc_t, b_fc, nullptr, nullptr, hbuf, NTOK, 4096, 1024);
    // out = h @ w_proj + b_proj + x1
    gemm_kernel<1><<<(NTOK / 128) * (1024 / 128), 256, 0, stream>>>(
        hbuf, wproj_t, b_proj, x1, out, nullptr, NTOK, 1024, 4096);
}

// Round 6
// 426.041 us; speedup vs baseline: 1.8904x; 1.2924x over previous
//
#include <hip/hip_runtime.h>
#include <hip/hip_bf16.h>
#include <math.h>

#define N_EMBED 1024
#define N_HEAD 16
#define HD 64
#define BB 4
#define TT 2048
#define NTOK (BB * TT)        // 8192 rows
#define QKV_LD (3 * N_EMBED)  // 3072

typedef __bf16 bf16x8 __attribute__((ext_vector_type(8)));
typedef float f32x4 __attribute__((ext_vector_type(4)));

__device__ __forceinline__ unsigned short f2bf(float f) {
    __hip_bfloat16 h = __float2bfloat16(f);
    return __builtin_bit_cast(unsigned short, h);
}

// async global->LDS, 16B per lane. LDS dest = wave-uniform base + lane*16.
__device__ __forceinline__ void gll16(const unsigned short* g, unsigned short* l) {
    __builtin_amdgcn_global_load_lds(
        (const __attribute__((address_space(1))) void*)g,
        (__attribute__((address_space(3))) void*)l,
        16, 0, 0);
}

// ---------------------------------------------------------------------------
// Weight transpose + fp32 -> bf16 convert:  in [K][N] fp32  ->  out [N][K] bf16
// ---------------------------------------------------------------------------
__global__ __launch_bounds__(256) void transpose_bf16_kernel(
    const float* __restrict__ in, unsigned short* __restrict__ out, int K, int N) {
    __shared__ float tile[32][33];
    int bx = blockIdx.x * 32;  // n base
    int by = blockIdx.y * 32;  // k base
    int tx = threadIdx.x, ty = threadIdx.y;
#pragma unroll
    for (int i = ty; i < 32; i += 8)
        tile[i][tx] = in[(size_t)(by + i) * N + bx + tx];
    __syncthreads();
#pragma unroll
    for (int i = ty; i < 32; i += 8)
        out[(size_t)(bx + i) * K + by + tx] = f2bf(tile[tx][i]);
}

// ---------------------------------------------------------------------------
// V transpose: qkv [B*T][3072] (v at col 2048+h*64) -> vt [b*16+h][64][2048]
// ---------------------------------------------------------------------------
__global__ __launch_bounds__(256) void transpose_v_kernel(
    const unsigned short* __restrict__ qkv, unsigned short* __restrict__ vt) {
    __shared__ unsigned short tile[32][33];
    int z = blockIdx.z;
    int b = z >> 4, h = z & 15;
    int t0 = blockIdx.x * 32, d0 = blockIdx.y * 32;
    int tx = threadIdx.x, ty = threadIdx.y;
    const unsigned short* src = qkv + (size_t)(b * TT) * QKV_LD + 2 * N_EMBED + h * HD;
#pragma unroll
    for (int i = ty; i < 32; i += 8)
        tile[i][tx] = src[(size_t)(t0 + i) * QKV_LD + d0 + tx];
    __syncthreads();
    unsigned short* dst = vt + (size_t)z * HD * TT;
#pragma unroll
    for (int i = ty; i < 32; i += 8)
        dst[(size_t)(d0 + i) * TT + t0 + tx] = tile[tx][i];
}

// ---------------------------------------------------------------------------
// Row LayerNorm: fp32 in [rows][1024] -> bf16 out
// ---------------------------------------------------------------------------
__global__ __launch_bounds__(256) void ln_kernel(
    const float* __restrict__ x, const float* __restrict__ w,
    const float* __restrict__ b, unsigned short* __restrict__ out) {
    int row = blockIdx.x;
    int t = threadIdx.x;
    const float* xr = x + (size_t)row * N_EMBED;
    float4 v = reinterpret_cast<const float4*>(xr)[t];
    float s = v.x + v.y + v.z + v.w;
    float s2 = v.x * v.x + v.y * v.y + v.z * v.z + v.w * v.w;
#pragma unroll
    for (int m = 1; m < 64; m <<= 1) {
        s += __shfl_xor(s, m);
        s2 += __shfl_xor(s2, m);
    }
    __shared__ float red[8];
    int wv = t >> 6, ln = t & 63;
    if (ln == 0) { red[wv] = s; red[wv + 4] = s2; }
    __syncthreads();
    s = red[0] + red[1] + red[2] + red[3];
    s2 = red[4] + red[5] + red[6] + red[7];
    float mu = s * (1.0f / N_EMBED);
    float var = s2 * (1.0f / N_EMBED) - mu * mu;
    float r = rsqrtf(var + 1e-5f);
    float4 wv4 = reinterpret_cast<const float4*>(w)[t];
    float4 bv4 = reinterpret_cast<const float4*>(b)[t];
    ushort4 o;
    o.x = f2bf((v.x - mu) * r * wv4.x + bv4.x);
    o.y = f2bf((v.y - mu) * r * wv4.y + bv4.y);
    o.z = f2bf((v.z - mu) * r * wv4.z + bv4.z);
    o.w = f2bf((v.w - mu) * r * wv4.w + bv4.w);
    *reinterpret_cast<ushort4*>(out + (size_t)row * N_EMBED + t * 4) = o;
}

// ---------------------------------------------------------------------------
// bf16 GEMM: C[M][N] = A[M][K] @ BT[N][K]^T + bias. m97 structure + XCD
// swizzle + 2-phase double-buffered staging (stage k+1 while computing k,
// one __syncthreads per K-step -> DMA latency hidden under MFMA).
// ---------------------------------------------------------------------------
template <int EPI>
__global__ __launch_bounds__(256) void gemm_kernel(
    const unsigned short* __restrict__ A,   // [M][K] bf16
    const unsigned short* __restrict__ BT,  // [N][K] bf16
    const float* __restrict__ bias,         // [N]
    const float* __restrict__ resid,        // [M][N] fp32 or nullptr
    float* __restrict__ outf,               // [M][N] fp32 (EPI 1)
    unsigned short* __restrict__ outb,      // [M][N] bf16 (EPI 0,2)
    int M, int N, int K) {
    __shared__ __align__(16) unsigned short As[2][128 * 32];
    __shared__ __align__(16) unsigned short Bs[2][128 * 32];
    int nbn = N >> 7;
    int nwg = gridDim.x;
    int orig = blockIdx.x;
    int swz = (orig & 7) * (nwg >> 3) + (orig >> 3);
    int bm = swz / nbn, bn = swz % nbn;
    int t = threadIdx.x;
    int lane = t & 63, wv = t >> 6;
    int wm = wv >> 1, wn = wv & 1;
    int mr = lane & 15, kg = lane >> 4;

    f32x4 acc[4][4];
#pragma unroll
    for (int i = 0; i < 4; i++)
#pragma unroll
        for (int j = 0; j < 4; j++) acc[i][j] = (f32x4){0.f, 0.f, 0.f, 0.f};

    int srow = t >> 2, sq = t & 3;
    const unsigned short* gA1 = A + (size_t)(bm * 128 + srow) * K + sq * 8;
    const unsigned short* gA2 = gA1 + (size_t)64 * K;
    const unsigned short* gB1 = BT + (size_t)(bn * 128 + srow) * K + sq * 8;
    const unsigned short* gB2 = gB1 + (size_t)64 * K;
    int w512 = wv * 512;

    // prologue: stage k-step 0 into buffer 0
    gll16(gA1, As[0] + w512);
    gll16(gA2, As[0] + 2048 + w512);
    gll16(gB1, Bs[0] + w512);
    gll16(gB2, Bs[0] + 2048 + w512);
    __syncthreads();

    int nk = K >> 5;
    for (int ki = 0; ki < nk; ki++) {
        int cur = ki & 1;
        if (ki + 1 < nk) {
            int k0 = (ki + 1) << 5;
            gll16(gA1 + k0, As[cur ^ 1] + w512);
            gll16(gA2 + k0, As[cur ^ 1] + 2048 + w512);
            gll16(gB1 + k0, Bs[cur ^ 1] + w512);
            gll16(gB2 + k0, Bs[cur ^ 1] + 2048 + w512);
        }
        bf16x8 af[4], bfr[4];
#pragma unroll
        for (int i = 0; i < 4; i++)
            af[i] = *reinterpret_cast<const bf16x8*>(&As[cur][(wm * 64 + i * 16 + mr) * 32 + kg * 8]);
#pragma unroll
        for (int j = 0; j < 4; j++)
            bfr[j] = *reinterpret_cast<const bf16x8*>(&Bs[cur][(wn * 64 + j * 16 + mr) * 32 + kg * 8]);
#pragma unroll
        for (int i = 0; i < 4; i++)
#pragma unroll
            for (int j = 0; j < 4; j++)
                acc[i][j] = __builtin_amdgcn_mfma_f32_16x16x32_bf16(af[i], bfr[j], acc[i][j], 0, 0, 0);
        __syncthreads();  // drains staging DMAs (vmcnt0) + ds reads; buf swap safe
    }

#pragma unroll
    for (int i = 0; i < 4; i++)
#pragma unroll
        for (int j = 0; j < 4; j++) {
            int n = bn * 128 + wn * 64 + j * 16 + mr;
            float bs = bias[n];
#pragma unroll
            for (int r = 0; r < 4; r++) {
                int m = bm * 128 + wm * 64 + i * 16 + kg * 4 + r;
                size_t idx = (size_t)m * N + n;
                float v = acc[i][j][r] + bs;
                if (EPI == 0) {
                    outb[idx] = f2bf(v);
                } else if (EPI == 1) {
                    outf[idx] = v + resid[idx];
                } else {
                    float g = 0.5f * v * (1.0f + erff(v * 0.70710678118f));
                    outb[idx] = f2bf(g);
                }
            }
        }
}

// ---------------------------------------------------------------------------
// Flash-style causal attention, SWAPPED QK^T (S^T = K·Q^T) so each lane owns
// one q-row: softmax reduce = in-lane + 2 shfl; P^T written as ds_write_b64,
// read back as ds_read_b128 B-frags. K/V triple-buffered LDS via
// global_load_lds, counted vmcnt(4) + raw s_barrier (round-5 schedule).
// 512 blocks: wid = qp*64 + bh so a bh's 8 blocks share an XCD (L2-resident
// K/V). Items {qt=qp, 15-qp} -> exactly 34 KV-tile iterations per block.
// LDS: K 3x8KB + V 3x8KB + P^T 16KB = 64KB -> 2 blocks/CU.
// ---------------------------------------------------------------------------
__global__ __launch_bounds__(256) void attn_kernel(
    const unsigned short* __restrict__ qkv,
    const unsigned short* __restrict__ vt,
    unsigned short* __restrict__ ctx) {
    __shared__ __align__(16) unsigned short Kb[3][4096];
    __shared__ __align__(16) unsigned short Vb[3][4096];
    __shared__ __align__(16) unsigned short PT[8192];  // [128 q][64 kv], swizzled
    const float SCL = 0.18033688011112042f;  // 0.125 * log2(e)
    int t = threadIdx.x, lane = t & 63, wv = t >> 6;
    int mr = lane & 15, kg = lane >> 4;

    int wid = blockIdx.x;          // qp*64 + bh  (same-bh blocks = same XCD)
    int bh = wid & 63, qp2 = wid >> 6;
    int h = bh & 15, b = bh >> 4;

    const unsigned short* qptr = qkv + (size_t)(b * TT) * QKV_LD + h * HD;
    const unsigned short* kp = qptr + N_EMBED;
    const unsigned short* vtp = vt + (size_t)bh * HD * TT;

    // staging geometry: call i covers 16B-chunks i*256 + wv*64 + lane
    int srow[2], scol[2], sbase[2];
#pragma unroll
    for (int i = 0; i < 2; i++) {
        int L = i * 256 + wv * 64 + lane;
        int row = L >> 3, slot = L & 7;
        srow[i] = row;
        scol[i] = (slot ^ (row & 7)) * 8;    // pre-swizzled global source chunk
        sbase[i] = (i * 256 + wv * 64) * 8;  // wave-uniform LDS base (ushorts)
    }
    const int csw = mr & 7;  // read-side chunk XOR (row & 7, rows = *16 + mr)

    auto stage = [&](int tile, int bi) {
        int kv0 = tile * 64;
#pragma unroll
        for (int i = 0; i < 2; i++) {
            gll16(kp + (size_t)(kv0 + srow[i]) * QKV_LD + scol[i], &Kb[bi][sbase[i]]);
            gll16(vtp + (size_t)srow[i] * TT + kv0 + scol[i], &Vb[bi][sbase[i]]);
        }
    };

    for (int item = 0; item < 2; ++item) {
        int qt = (item == 0) ? qp2 : 15 - qp2;
        int ntiles = 2 * qt + 2;
        int qbase = qt * 128 + wv * 32;

        // Q as B-operand: col n = mr -> q-row qbase+f*16+mr, k = c*32+kg*8+e
        bf16x8 aq[2][2];
#pragma unroll
        for (int f = 0; f < 2; f++)
#pragma unroll
            for (int c = 0; c < 2; c++)
                aq[f][c] = *reinterpret_cast<const bf16x8*>(
                    qptr + (size_t)(qbase + f * 16 + mr) * QKV_LD + c * 32 + kg * 8);

        // O^T accumulators: col = q = mr, row = d = jd*16 + kg*4 + r
        f32x4 Oa[2][4];
#pragma unroll
        for (int f = 0; f < 2; f++)
#pragma unroll
            for (int jd = 0; jd < 4; jd++) Oa[f][jd] = (f32x4){0.f, 0.f, 0.f, 0.f};
        float mrow[2] = {-3.0e38f, -3.0e38f};
        float lrow[2] = {0.f, 0.f};

        stage(0, 0);
        stage(1, 1);

        for (int tl = 0; tl < ntiles; ++tl) {
            if (tl + 1 < ntiles) {
                asm volatile("s_waitcnt vmcnt(4)" ::: "memory");
            } else {
                asm volatile("s_waitcnt vmcnt(0)" ::: "memory");
            }
            __builtin_amdgcn_s_barrier();
            int t2 = tl + 2;
            if (t2 < ntiles) stage(t2, t2 % 3);

            int bi = tl % 3;
            int kv0 = tl * 64;
            const unsigned short* Kt = Kb[bi];
            const unsigned short* Vt = Vb[bi];

            // S^T = K·Q^T : lane holds S[q=qbase+f*16+mr][kv=kv0+j*16+kg*4+r]
            f32x4 sf[2][4];
#pragma unroll
            for (int j = 0; j < 4; j++) {
                int rl = j * 16 + mr;
                bf16x8 bk0 = *reinterpret_cast<const bf16x8*>(&Kt[rl * 64 + (kg ^ csw) * 8]);
                bf16x8 bk1 = *reinterpret_cast<const bf16x8*>(&Kt[rl * 64 + ((4 + kg) ^ csw) * 8]);
#pragma unroll
                for (int f = 0; f < 2; f++) {
                    f32x4 s = (f32x4){0.f, 0.f, 0.f, 0.f};
                    s = __builtin_amdgcn_mfma_f32_16x16x32_bf16(bk0, aq[f][0], s, 0, 0, 0);
                    s = __builtin_amdgcn_mfma_f32_16x16x32_bf16(bk1, aq[f][1], s, 0, 0, 0);
                    sf[f][j] = s;
                }
            }

            bool dmask = (tl >= 2 * qt);  // only last two tiles touch the diagonal
#pragma unroll
            for (int f = 0; f < 2; f++) {
                int qrow = qbase + f * 16 + mr;
                int R = wv * 32 + f * 16 + mr;
                // scale + mask + in-lane max over this lane's 16 kv values
                float mx = -3.0e38f;
#pragma unroll
                for (int j = 0; j < 4; j++)
#pragma unroll
                    for (int r = 0; r < 4; r++) {
                        float sv = sf[f][j][r] * SCL;
                        if (dmask && (kv0 + j * 16 + kg * 4 + r > qrow)) sv = -3.0e38f;
                        sf[f][j][r] = sv;
                        mx = fmaxf(mx, sv);
                    }
                mx = fmaxf(mx, __shfl_xor(mx, 16));
                mx = fmaxf(mx, __shfl_xor(mx, 32));
                float mn = fmaxf(mrow[f], mx);
                float al = __builtin_amdgcn_exp2f(mrow[f] - mn);
                mrow[f] = mn;
#pragma unroll
                for (int jd = 0; jd < 4; jd++) Oa[f][jd] *= al;
                float ps = 0.f;
#pragma unroll
                for (int j = 0; j < 4; j++)
#pragma unroll
                    for (int r = 0; r < 4; r++) {
                        float p = __builtin_amdgcn_exp2f(sf[f][j][r] - mn);
                        sf[f][j][r] = p;
                        ps += p;
                    }
                ps += __shfl_xor(ps, 16);
                ps += __shfl_xor(ps, 32);
                lrow[f] = lrow[f] * al + ps;
                // P^T -> LDS: 4 consecutive kv per (j): ds_write_b64, swizzled
                int rsw = R & 7;
#pragma unroll
                for (int j = 0; j < 4; j++) {
                    unsigned lo = (unsigned)f2bf(sf[f][j][0]) | ((unsigned)f2bf(sf[f][j][1]) << 16);
                    unsigned hi = (unsigned)f2bf(sf[f][j][2]) | ((unsigned)f2bf(sf[f][j][3]) << 16);
                    int cw = 2 * j + (kg >> 1);
                    int addr = R * 64 + ((cw ^ rsw) << 3) + (kg & 1) * 4;
                    uint2 pk; pk.x = lo; pk.y = hi;
                    *reinterpret_cast<uint2*>(&PT[addr]) = pk;
                }
            }

            // O^T += V^T · P^T  (V^T as A: row=d=jd*16+mr; P^T as B: col=q=mr)
#pragma unroll
            for (int c = 0; c < 2; c++) {
                int R0 = wv * 32 + mr, R1 = R0 + 16;
                bf16x8 pb0 = *reinterpret_cast<const bf16x8*>(
                    &PT[R0 * 64 + (((c * 4 + kg) ^ (R0 & 7)) << 3)]);
                bf16x8 pb1 = *reinterpret_cast<const bf16x8*>(
                    &PT[R1 * 64 + (((c * 4 + kg) ^ (R1 & 7)) << 3)]);
#pragma unroll
                for (int jd = 0; jd < 4; jd++) {
                    int rv = jd * 16 + mr;
                    bf16x8 vf = *reinterpret_cast<const bf16x8*>(
                        &Vt[rv * 64 + (((c * 4 + kg) ^ (rv & 7)) << 3)]);
                    Oa[0][jd] = __builtin_amdgcn_mfma_f32_16x16x32_bf16(vf, pb0, Oa[0][jd], 0, 0, 0);
                    Oa[1][jd] = __builtin_amdgcn_mfma_f32_16x16x32_bf16(vf, pb1, Oa[1][jd], 0, 0, 0);
                }
            }
        }

        // epilogue: ctx[q][h*64+d] = O/l ; lane writes 4 consecutive d (8B)
#pragma unroll
        for (int f = 0; f < 2; f++) {
            float iv = 1.0f / lrow[f];
            int q = qbase + f * 16 + mr;
#pragma unroll
            for (int jd = 0; jd < 4; jd++) {
                ushort4 o;
                o.x = f2bf(Oa[f][jd][0] * iv);
                o.y = f2bf(Oa[f][jd][1] * iv);
                o.z = f2bf(Oa[f][jd][2] * iv);
                o.w = f2bf(Oa[f][jd][3] * iv);
                *reinterpret_cast<ushort4*>(
                    ctx + (size_t)(b * TT + q) * N_EMBED + h * HD + jd * 16 + kg * 4) = o;
            }
        }
        __syncthreads();  // buffers free before next item's prologue staging
    }
}

// ---------------------------------------------------------------------------
extern "C" void kernel_launch(void* const* d_in, const int* in_sizes, int n_in,
                              void* d_out, int out_size, void* d_ws, size_t ws_size,
                              hipStream_t stream) {
    const float* x      = (const float*)d_in[0];
    const float* ln1_w  = (const float*)d_in[1];
    const float* ln1_b  = (const float*)d_in[2];
    const float* w_qkv  = (const float*)d_in[3];
    const float* b_qkv  = (const float*)d_in[4];
    const float* w_o    = (const float*)d_in[5];
    const float* b_o    = (const float*)d_in[6];
    const float* ln2_w  = (const float*)d_in[7];
    const float* ln2_b  = (const float*)d_in[8];
    const float* w_fc   = (const float*)d_in[9];
    const float* b_fc   = (const float*)d_in[10];
    const float* w_proj = (const float*)d_in[11];
    const float* b_proj = (const float*)d_in[12];
    float* out = (float*)d_out;

    char* ws = (char*)d_ws;
    size_t off = 0;
    auto alloc = [&](size_t bytes) -> void* {
        void* p = ws + off;
        off += (bytes + 255) & ~(size_t)255;
        return p;
    };
    unsigned short* wqkv_t  = (unsigned short*)alloc((size_t)3072 * 1024 * 2);
    unsigned short* wo_t    = (unsigned short*)alloc((size_t)1024 * 1024 * 2);
    unsigned short* wfc_t   = (unsigned short*)alloc((size_t)4096 * 1024 * 2);
    unsigned short* wproj_t = (unsigned short*)alloc((size_t)1024 * 4096 * 2);
    unsigned short* lnb     = (unsigned short*)alloc((size_t)NTOK * 1024 * 2);
    float*          x1      = (float*)alloc((size_t)NTOK * 1024 * 4);
    unsigned short* qkv     = (unsigned short*)alloc((size_t)NTOK * 3072 * 2);
    unsigned short* ctxb    = (unsigned short*)alloc((size_t)NTOK * 1024 * 2);
    unsigned short* hbuf    = qkv;                 // overlays qkv (dead after attn)
    unsigned short* vt      = (unsigned short*)x1; // overlays x1 (written after attn)

    dim3 tb32(32, 8);
    transpose_bf16_kernel<<<dim3(3072 / 32, 1024 / 32), tb32, 0, stream>>>(w_qkv, wqkv_t, 1024, 3072);
    transpose_bf16_kernel<<<dim3(1024 / 32, 1024 / 32), tb32, 0, stream>>>(w_o, wo_t, 1024, 1024);
    transpose_bf16_kernel<<<dim3(4096 / 32, 1024 / 32), tb32, 0, stream>>>(w_fc, wfc_t, 1024, 4096);
    transpose_bf16_kernel<<<dim3(1024 / 32, 4096 / 32), tb32, 0, stream>>>(w_proj, wproj_t, 4096, 1024);

    // ln1(x) -> lnb
    ln_kernel<<<NTOK, 256, 0, stream>>>(x, ln1_w, ln1_b, lnb);
    // qkv = lnb @ w_qkv + b_qkv
    gemm_kernel<0><<<(NTOK / 128) * (3072 / 128), 256, 0, stream>>>(
        lnb, wqkv_t, b_qkv, nullptr, nullptr, qkv, NTOK, 3072, 1024);
    // V transpose -> vt
    transpose_v_kernel<<<dim3(TT / 32, HD / 32, BB * N_HEAD), tb32, 0, stream>>>(qkv, vt);
    // attention -> ctx  (512 blocks, bh-major XCD grouping, LPT-paired)
    attn_kernel<<<512, 256, 0, stream>>>(qkv, vt, ctxb);
    // x1 = ctx @ w_o + b_o + x   (x1 overwrites vt region — vt dead now)
    gemm_kernel<1><<<(NTOK / 128) * (1024 / 128), 256, 0, stream>>>(
        ctxb, wo_t, b_o, x, x1, nullptr, NTOK, 1024, 1024);
    // ln2(x1) -> lnb
    ln_kernel<<<NTOK, 256, 0, stream>>>(x1, ln2_w, ln2_b, lnb);
    // h = gelu(lnb @ w_fc + b_fc)
    gemm_kernel<2><<<(NTOK / 128) * (4096 / 128), 256, 0, stream>>>(
        lnb, wfc_t, b_fc, nullptr, nullptr, hbuf, NTOK, 4096, 1024);
    // out = h @ w_proj + b_proj + x1
    gemm_kernel<1><<<(NTOK / 128) * (1024 / 128), 256, 0, stream>>>(
        hbuf, wproj_t, b_proj, x1, out, nullptr, NTOK, 1024, 4096);
}

// Round 8
// 424.311 us; speedup vs baseline: 1.8981x; 1.0041x over previous
//
#include <hip/hip_runtime.h>
#include <hip/hip_bf16.h>
#include <math.h>

#define N_EMBED 1024
#define N_HEAD 16
#define HD 64
#define BB 4
#define TT 2048
#define NTOK (BB * TT)        // 8192 rows
#define QKV_LD (3 * N_EMBED)  // 3072

typedef __bf16 bf16x8 __attribute__((ext_vector_type(8)));
typedef float f32x4 __attribute__((ext_vector_type(4)));

__device__ __forceinline__ unsigned short f2bf(float f) {
    __hip_bfloat16 h = __float2bfloat16(f);
    return __builtin_bit_cast(unsigned short, h);
}

// async global->LDS, 16B per lane. LDS dest = wave-uniform base + lane*16.
__device__ __forceinline__ void gll16(const unsigned short* g, unsigned short* l) {
    __builtin_amdgcn_global_load_lds(
        (const __attribute__((address_space(1))) void*)g,
        (__attribute__((address_space(3))) void*)l,
        16, 0, 0);
}

// ---------------------------------------------------------------------------
// Weight transpose + fp32 -> bf16 convert:  in [K][N] fp32  ->  out [N][K] bf16
// ---------------------------------------------------------------------------
__global__ __launch_bounds__(256) void transpose_bf16_kernel(
    const float* __restrict__ in, unsigned short* __restrict__ out, int K, int N) {
    __shared__ float tile[32][33];
    int bx = blockIdx.x * 32;  // n base
    int by = blockIdx.y * 32;  // k base
    int tx = threadIdx.x, ty = threadIdx.y;
#pragma unroll
    for (int i = ty; i < 32; i += 8)
        tile[i][tx] = in[(size_t)(by + i) * N + bx + tx];
    __syncthreads();
#pragma unroll
    for (int i = ty; i < 32; i += 8)
        out[(size_t)(bx + i) * K + by + tx] = f2bf(tile[tx][i]);
}

// ---------------------------------------------------------------------------
// V transpose: qkv [B*T][3072] (v at col 2048+h*64) -> vt [b*16+h][64][2048]
// ---------------------------------------------------------------------------
__global__ __launch_bounds__(256) void transpose_v_kernel(
    const unsigned short* __restrict__ qkv, unsigned short* __restrict__ vt) {
    __shared__ unsigned short tile[32][33];
    int z = blockIdx.z;
    int b = z >> 4, h = z & 15;
    int t0 = blockIdx.x * 32, d0 = blockIdx.y * 32;
    int tx = threadIdx.x, ty = threadIdx.y;
    const unsigned short* src = qkv + (size_t)(b * TT) * QKV_LD + 2 * N_EMBED + h * HD;
#pragma unroll
    for (int i = ty; i < 32; i += 8)
        tile[i][tx] = src[(size_t)(t0 + i) * QKV_LD + d0 + tx];
    __syncthreads();
    unsigned short* dst = vt + (size_t)z * HD * TT;
#pragma unroll
    for (int i = ty; i < 32; i += 8)
        dst[(size_t)(d0 + i) * TT + t0 + tx] = tile[tx][i];
}

// ---------------------------------------------------------------------------
// Row LayerNorm: fp32 in [rows][1024] -> bf16 out
// ---------------------------------------------------------------------------
__global__ __launch_bounds__(256) void ln_kernel(
    const float* __restrict__ x, const float* __restrict__ w,
    const float* __restrict__ b, unsigned short* __restrict__ out) {
    int row = blockIdx.x;
    int t = threadIdx.x;
    const float* xr = x + (size_t)row * N_EMBED;
    float4 v = reinterpret_cast<const float4*>(xr)[t];
    float s = v.x + v.y + v.z + v.w;
    float s2 = v.x * v.x + v.y * v.y + v.z * v.z + v.w * v.w;
#pragma unroll
    for (int m = 1; m < 64; m <<= 1) {
        s += __shfl_xor(s, m);
        s2 += __shfl_xor(s2, m);
    }
    __shared__ float red[8];
    int wv = t >> 6, ln = t & 63;
    if (ln == 0) { red[wv] = s; red[wv + 4] = s2; }
    __syncthreads();
    s = red[0] + red[1] + red[2] + red[3];
    s2 = red[4] + red[5] + red[6] + red[7];
    float mu = s * (1.0f / N_EMBED);
    float var = s2 * (1.0f / N_EMBED) - mu * mu;
    float r = rsqrtf(var + 1e-5f);
    float4 wv4 = reinterpret_cast<const float4*>(w)[t];
    float4 bv4 = reinterpret_cast<const float4*>(b)[t];
    ushort4 o;
    o.x = f2bf((v.x - mu) * r * wv4.x + bv4.x);
    o.y = f2bf((v.y - mu) * r * wv4.y + bv4.y);
    o.z = f2bf((v.z - mu) * r * wv4.z + bv4.z);
    o.w = f2bf((v.w - mu) * r * wv4.w + bv4.w);
    *reinterpret_cast<ushort4*>(out + (size_t)row * N_EMBED + t * 4) = o;
}

// ---------------------------------------------------------------------------
// bf16 GEMM: C[M][N] = A[M][K] @ BT[N][K]^T + bias. 128x128 tile, BK=32,
// TRIPLE-buffered LDS staging via global_load_lds with counted vmcnt(4) +
// raw s_barrier (tile t+1/t+2 stay in flight across the barrier), XCD
// swizzle, and T2 source-side XOR chunk swizzle (conflict-free ds_read_b128:
// chunk ^= (row>>1)&3 on both the staged global source and the read).
// ---------------------------------------------------------------------------
template <int EPI>
__global__ __launch_bounds__(256) void gemm_kernel(
    const unsigned short* __restrict__ A,   // [M][K] bf16
    const unsigned short* __restrict__ BT,  // [N][K] bf16
    const float* __restrict__ bias,         // [N]
    const float* __restrict__ resid,        // [M][N] fp32 or nullptr
    float* __restrict__ outf,               // [M][N] fp32 (EPI 1)
    unsigned short* __restrict__ outb,      // [M][N] bf16 (EPI 0,2)
    int M, int N, int K) {
    __shared__ __align__(16) unsigned short As[3][128 * 32];
    __shared__ __align__(16) unsigned short Bs[3][128 * 32];
    int nbn = N >> 7;
    int nwg = gridDim.x;
    int orig = blockIdx.x;
    int swz = (orig & 7) * (nwg >> 3) + (orig >> 3);
    int bm = swz / nbn, bn = swz % nbn;
    int t = threadIdx.x;
    int lane = t & 63, wv = t >> 6;
    int wm = wv >> 1, wn = wv & 1;
    int mr = lane & 15, kg = lane >> 4;

    f32x4 acc[4][4];
#pragma unroll
    for (int i = 0; i < 4; i++)
#pragma unroll
        for (int j = 0; j < 4; j++) acc[i][j] = (f32x4){0.f, 0.f, 0.f, 0.f};

    // staging: thread t owns row srow (and srow+64), 16B chunk sq of each row.
    // Source chunk XOR'd with (row>>1)&3 (same for row and row+64) so the
    // LDS image is chunk-swizzled while the DMA dest stays linear.
    int srow = t >> 2, sq = t & 3;
    int sqs = sq ^ ((srow >> 1) & 3);
    const unsigned short* gA1 = A + (size_t)(bm * 128 + srow) * K + sqs * 8;
    const unsigned short* gA2 = gA1 + (size_t)64 * K;
    const unsigned short* gB1 = BT + (size_t)(bn * 128 + srow) * K + sqs * 8;
    const unsigned short* gB2 = gB1 + (size_t)64 * K;
    int w512 = wv * 512;

    auto stageg = [&](int ki, int bi) {
        int k0 = ki << 5;
        gll16(gA1 + k0, As[bi] + w512);
        gll16(gA2 + k0, As[bi] + 2048 + w512);
        gll16(gB1 + k0, Bs[bi] + w512);
        gll16(gB2 + k0, Bs[bi] + 2048 + w512);
    };

    int nk = K >> 5;
    stageg(0, 0);
    stageg(1, 1);

    const int csw = (mr >> 1) & 3;  // read-side chunk XOR
    for (int ki = 0; ki < nk; ki++) {
        // my 4 chunks of tile ki have landed; tile ki+1's 4 stay in flight
        if (ki + 1 < nk) {
            asm volatile("s_waitcnt vmcnt(4)" ::: "memory");
        } else {
            asm volatile("s_waitcnt vmcnt(0)" ::: "memory");
        }
        __builtin_amdgcn_s_barrier();
        if (ki + 2 < nk) stageg(ki + 2, (ki + 2) % 3);

        int cur = ki % 3;
        bf16x8 af[4], bfr[4];
#pragma unroll
        for (int i = 0; i < 4; i++)
            af[i] = *reinterpret_cast<const bf16x8*>(
                &As[cur][(wm * 64 + i * 16 + mr) * 32 + ((kg ^ csw) * 8)]);
#pragma unroll
        for (int j = 0; j < 4; j++)
            bfr[j] = *reinterpret_cast<const bf16x8*>(
                &Bs[cur][(wn * 64 + j * 16 + mr) * 32 + ((kg ^ csw) * 8)]);
#pragma unroll
        for (int i = 0; i < 4; i++)
#pragma unroll
            for (int j = 0; j < 4; j++)
                acc[i][j] = __builtin_amdgcn_mfma_f32_16x16x32_bf16(af[i], bfr[j], acc[i][j], 0, 0, 0);
    }

#pragma unroll
    for (int i = 0; i < 4; i++)
#pragma unroll
        for (int j = 0; j < 4; j++) {
            int n = bn * 128 + wn * 64 + j * 16 + mr;
            float bs = bias[n];
#pragma unroll
            for (int r = 0; r < 4; r++) {
                int m = bm * 128 + wm * 64 + i * 16 + kg * 4 + r;
                size_t idx = (size_t)m * N + n;
                float v = acc[i][j][r] + bs;
                if (EPI == 0) {
                    outb[idx] = f2bf(v);
                } else if (EPI == 1) {
                    outf[idx] = v + resid[idx];
                } else {
                    float g = 0.5f * v * (1.0f + erff(v * 0.70710678118f));
                    outb[idx] = f2bf(g);
                }
            }
        }
}

// ---------------------------------------------------------------------------
// Flash-style causal attention, SWAPPED QK^T (S^T = K·Q^T) so each lane owns
// one q-row: softmax reduce = in-lane + 2 shfl; P^T written as ds_write_b64,
// read back as ds_read_b128 B-frags. K/V triple-buffered LDS via
// global_load_lds, counted vmcnt(4) + raw s_barrier.
// 512 blocks: wid = qp*64 + bh so a bh's 8 blocks share an XCD (L2-resident
// K/V). Items {qt=qp, 15-qp} -> exactly 34 KV-tile iterations per block.
// LDS: K 3x8KB + V 3x8KB + P^T 16KB = 64KB -> 2 blocks/CU.
// ---------------------------------------------------------------------------
__global__ __launch_bounds__(256) void attn_kernel(
    const unsigned short* __restrict__ qkv,
    const unsigned short* __restrict__ vt,
    unsigned short* __restrict__ ctx) {
    __shared__ __align__(16) unsigned short Kb[3][4096];
    __shared__ __align__(16) unsigned short Vb[3][4096];
    __shared__ __align__(16) unsigned short PT[8192];  // [128 q][64 kv], swizzled
    const float SCL = 0.18033688011112042f;  // 0.125 * log2(e)
    int t = threadIdx.x, lane = t & 63, wv = t >> 6;
    int mr = lane & 15, kg = lane >> 4;

    int wid = blockIdx.x;          // qp*64 + bh  (same-bh blocks = same XCD)
    int bh = wid & 63, qp2 = wid >> 6;
    int h = bh & 15, b = bh >> 4;

    const unsigned short* qptr = qkv + (size_t)(b * TT) * QKV_LD + h * HD;
    const unsigned short* kp = qptr + N_EMBED;
    const unsigned short* vtp = vt + (size_t)bh * HD * TT;

    // staging geometry: call i covers 16B-chunks i*256 + wv*64 + lane
    int srow[2], scol[2], sbase[2];
#pragma unroll
    for (int i = 0; i < 2; i++) {
        int L = i * 256 + wv * 64 + lane;
        int row = L >> 3, slot = L & 7;
        srow[i] = row;
        scol[i] = (slot ^ (row & 7)) * 8;    // pre-swizzled global source chunk
        sbase[i] = (i * 256 + wv * 64) * 8;  // wave-uniform LDS base (ushorts)
    }
    const int csw = mr & 7;  // read-side chunk XOR (row & 7, rows = *16 + mr)

    auto stage = [&](int tile, int bi) {
        int kv0 = tile * 64;
#pragma unroll
        for (int i = 0; i < 2; i++) {
            gll16(kp + (size_t)(kv0 + srow[i]) * QKV_LD + scol[i], &Kb[bi][sbase[i]]);
            gll16(vtp + (size_t)srow[i] * TT + kv0 + scol[i], &Vb[bi][sbase[i]]);
        }
    };

    for (int item = 0; item < 2; ++item) {
        int qt = (item == 0) ? qp2 : 15 - qp2;
        int ntiles = 2 * qt + 2;
        int qbase = qt * 128 + wv * 32;

        // Q as B-operand: col n = mr -> q-row qbase+f*16+mr, k = c*32+kg*8+e
        bf16x8 aq[2][2];
#pragma unroll
        for (int f = 0; f < 2; f++)
#pragma unroll
            for (int c = 0; c < 2; c++)
                aq[f][c] = *reinterpret_cast<const bf16x8*>(
                    qptr + (size_t)(qbase + f * 16 + mr) * QKV_LD + c * 32 + kg * 8);

        // O^T accumulators: col = q = mr, row = d = jd*16 + kg*4 + r
        f32x4 Oa[2][4];
#pragma unroll
        for (int f = 0; f < 2; f++)
#pragma unroll
            for (int jd = 0; jd < 4; jd++) Oa[f][jd] = (f32x4){0.f, 0.f, 0.f, 0.f};
        float mrow[2] = {-3.0e38f, -3.0e38f};
        float lrow[2] = {0.f, 0.f};

        stage(0, 0);
        stage(1, 1);

        for (int tl = 0; tl < ntiles; ++tl) {
            if (tl + 1 < ntiles) {
                asm volatile("s_waitcnt vmcnt(4)" ::: "memory");
            } else {
                asm volatile("s_waitcnt vmcnt(0)" ::: "memory");
            }
            __builtin_amdgcn_s_barrier();
            int t2 = tl + 2;
            if (t2 < ntiles) stage(t2, t2 % 3);

            int bi = tl % 3;
            int kv0 = tl * 64;
            const unsigned short* Kt = Kb[bi];
            const unsigned short* Vt = Vb[bi];

            // S^T = K·Q^T : lane holds S[q=qbase+f*16+mr][kv=kv0+j*16+kg*4+r]
            f32x4 sf[2][4];
#pragma unroll
            for (int j = 0; j < 4; j++) {
                int rl = j * 16 + mr;
                bf16x8 bk0 = *reinterpret_cast<const bf16x8*>(&Kt[rl * 64 + (kg ^ csw) * 8]);
                bf16x8 bk1 = *reinterpret_cast<const bf16x8*>(&Kt[rl * 64 + ((4 + kg) ^ csw) * 8]);
#pragma unroll
                for (int f = 0; f < 2; f++) {
                    f32x4 s = (f32x4){0.f, 0.f, 0.f, 0.f};
                    s = __builtin_amdgcn_mfma_f32_16x16x32_bf16(bk0, aq[f][0], s, 0, 0, 0);
                    s = __builtin_amdgcn_mfma_f32_16x16x32_bf16(bk1, aq[f][1], s, 0, 0, 0);
                    sf[f][j] = s;
                }
            }

            bool dmask = (tl >= 2 * qt);  // only last two tiles touch the diagonal
#pragma unroll
            for (int f = 0; f < 2; f++) {
                int qrow = qbase + f * 16 + mr;
                int R = wv * 32 + f * 16 + mr;
                // scale + mask + in-lane max over this lane's 16 kv values
                float mx = -3.0e38f;
#pragma unroll
                for (int j = 0; j < 4; j++)
#pragma unroll
                    for (int r = 0; r < 4; r++) {
                        float sv = sf[f][j][r] * SCL;
                        if (dmask && (kv0 + j * 16 + kg * 4 + r > qrow)) sv = -3.0e38f;
                        sf[f][j][r] = sv;
                        mx = fmaxf(mx, sv);
                    }
                mx = fmaxf(mx, __shfl_xor(mx, 16));
                mx = fmaxf(mx, __shfl_xor(mx, 32));
                float mn = fmaxf(mrow[f], mx);
                float al = __builtin_amdgcn_exp2f(mrow[f] - mn);
                mrow[f] = mn;
#pragma unroll
                for (int jd = 0; jd < 4; jd++) Oa[f][jd] *= al;
                float ps = 0.f;
#pragma unroll
                for (int j = 0; j < 4; j++)
#pragma unroll
                    for (int r = 0; r < 4; r++) {
                        float p = __builtin_amdgcn_exp2f(sf[f][j][r] - mn);
                        sf[f][j][r] = p;
                        ps += p;
                    }
                ps += __shfl_xor(ps, 16);
                ps += __shfl_xor(ps, 32);
                lrow[f] = lrow[f] * al + ps;
                // P^T -> LDS: 4 consecutive kv per (j): ds_write_b64, swizzled
                int rsw = R & 7;
#pragma unroll
                for (int j = 0; j < 4; j++) {
                    unsigned lo = (unsigned)f2bf(sf[f][j][0]) | ((unsigned)f2bf(sf[f][j][1]) << 16);
                    unsigned hi = (unsigned)f2bf(sf[f][j][2]) | ((unsigned)f2bf(sf[f][j][3]) << 16);
                    int cw = 2 * j + (kg >> 1);
                    int addr = R * 64 + ((cw ^ rsw) << 3) + (kg & 1) * 4;
                    uint2 pk; pk.x = lo; pk.y = hi;
                    *reinterpret_cast<uint2*>(&PT[addr]) = pk;
                }
            }

            // O^T += V^T · P^T  (V^T as A: row=d=jd*16+mr; P^T as B: col=q=mr)
#pragma unroll
            for (int c = 0; c < 2; c++) {
                int R0 = wv * 32 + mr, R1 = R0 + 16;
                bf16x8 pb0 = *reinterpret_cast<const bf16x8*>(
                    &PT[R0 * 64 + (((c * 4 + kg) ^ (R0 & 7)) << 3)]);
                bf16x8 pb1 = *reinterpret_cast<const bf16x8*>(
                    &PT[R1 * 64 + (((c * 4 + kg) ^ (R1 & 7)) << 3)]);
#pragma unroll
                for (int jd = 0; jd < 4; jd++) {
                    int rv = jd * 16 + mr;
                    bf16x8 vf = *reinterpret_cast<const bf16x8*>(
                        &Vt[rv * 64 + (((c * 4 + kg) ^ (rv & 7)) << 3)]);
                    Oa[0][jd] = __builtin_amdgcn_mfma_f32_16x16x32_bf16(vf, pb0, Oa[0][jd], 0, 0, 0);
                    Oa[1][jd] = __builtin_amdgcn_mfma_f32_16x16x32_bf16(vf, pb1, Oa[1][jd], 0, 0, 0);
                }
            }
        }

        // epilogue: ctx[q][h*64+d] = O/l ; lane writes 4 consecutive d (8B)
#pragma unroll
        for (int f = 0; f < 2; f++) {
            float iv = 1.0f / lrow[f];
            int q = qbase + f * 16 + mr;
#pragma unroll
            for (int jd = 0; jd < 4; jd++) {
                ushort4 o;
                o.x = f2bf(Oa[f][jd][0] * iv);
                o.y = f2bf(Oa[f][jd][1] * iv);
                o.z = f2bf(Oa[f][jd][2] * iv);
                o.w = f2bf(Oa[f][jd][3] * iv);
                *reinterpret_cast<ushort4*>(
                    ctx + (size_t)(b * TT + q) * N_EMBED + h * HD + jd * 16 + kg * 4) = o;
            }
        }
        __syncthreads();  // buffers free before next item's prologue staging
    }
}

// ---------------------------------------------------------------------------
extern "C" void kernel_launch(void* const* d_in, const int* in_sizes, int n_in,
                              void* d_out, int out_size, void* d_ws, size_t ws_size,
                              hipStream_t stream) {
    const float* x      = (const float*)d_in[0];
    const float* ln1_w  = (const float*)d_in[1];
    const float* ln1_b  = (const float*)d_in[2];
    const float* w_qkv  = (const float*)d_in[3];
    const float* b_qkv  = (const float*)d_in[4];
    const float* w_o    = (const float*)d_in[5];
    const float* b_o    = (const float*)d_in[6];
    const float* ln2_w  = (const float*)d_in[7];
    const float* ln2_b  = (const float*)d_in[8];
    const float* w_fc   = (const float*)d_in[9];
    const float* b_fc   = (const float*)d_in[10];
    const float* w_proj = (const float*)d_in[11];
    const float* b_proj = (const float*)d_in[12];
    float* out = (float*)d_out;

    char* ws = (char*)d_ws;
    size_t off = 0;
    auto alloc = [&](size_t bytes) -> void* {
        void* p = ws + off;
        off += (bytes + 255) & ~(size_t)255;
        return p;
    };
    unsigned short* wqkv_t  = (unsigned short*)alloc((size_t)3072 * 1024 * 2);
    unsigned short* wo_t    = (unsigned short*)alloc((size_t)1024 * 1024 * 2);
    unsigned short* wfc_t   = (unsigned short*)alloc((size_t)4096 * 1024 * 2);
    unsigned short* wproj_t = (unsigned short*)alloc((size_t)1024 * 4096 * 2);
    unsigned short* lnb     = (unsigned short*)alloc((size_t)NTOK * 1024 * 2);
    float*          x1      = (float*)alloc((size_t)NTOK * 1024 * 4);
    unsigned short* qkv     = (unsigned short*)alloc((size_t)NTOK * 3072 * 2);
    unsigned short* ctxb    = (unsigned short*)alloc((size_t)NTOK * 1024 * 2);
    unsigned short* hbuf    = qkv;                 // overlays qkv (dead after attn)
    unsigned short* vt      = (unsigned short*)x1; // overlays x1 (written after attn)

    dim3 tb32(32, 8);
    transpose_bf16_kernel<<<dim3(3072 / 32, 1024 / 32), tb32, 0, stream>>>(w_qkv, wqkv_t, 1024, 3072);
    transpose_bf16_kernel<<<dim3(1024 / 32, 1024 / 32), tb32, 0, stream>>>(w_o, wo_t, 1024, 1024);
    transpose_bf16_kernel<<<dim3(4096 / 32, 1024 / 32), tb32, 0, stream>>>(w_fc, wfc_t, 1024, 4096);
    transpose_bf16_kernel<<<dim3(1024 / 32, 4096 / 32), tb32, 0, stream>>>(w_proj, wproj_t, 4096, 1024);

    // ln1(x) -> lnb
    ln_kernel<<<NTOK, 256, 0, stream>>>(x, ln1_w, ln1_b, lnb);
    // qkv = lnb @ w_qkv + b_qkv
    gemm_kernel<0><<<(NTOK / 128) * (3072 / 128), 256, 0, stream>>>(
        lnb, wqkv_t, b_qkv, nullptr, nullptr, qkv, NTOK, 3072, 1024);
    // V transpose -> vt
    transpose_v_kernel<<<dim3(TT / 32, HD / 32, BB * N_HEAD), tb32, 0, stream>>>(qkv, vt);
    // attention -> ctx  (512 blocks, bh-major XCD grouping, LPT-paired)
    attn_kernel<<<512, 256, 0, stream>>>(qkv, vt, ctxb);
    // x1 = ctx @ w_o + b_o + x   (x1 overwrites vt region — vt dead now)
    gemm_kernel<1><<<(NTOK / 128) * (1024 / 128), 256, 0, stream>>>(
        ctxb, wo_t, b_o, x, x1, nullptr, NTOK, 1024, 1024);
    // ln2(x1) -> lnb
    ln_kernel<<<NTOK, 256, 0, stream>>>(x1, ln2_w, ln2_b, lnb);
    // h = gelu(lnb @ w_fc + b_fc)
    gemm_kernel<2><<<(NTOK / 128) * (4096 / 128), 256, 0, stream>>>(
        lnb, wfc_t, b_fc, nullptr, nullptr, hbuf, NTOK, 4096, 1024);
    // out = h @ w_proj + b_proj + x1
    gemm_kernel<1><<<(NTOK / 128) * (1024 / 128), 256, 0, stream>>>(
        hbuf, wproj_t, b_proj, x1, out, nullptr, NTOK, 1024, 4096);
}